// Round 12
// baseline (441.017 us; speedup 1.0000x reference)
//
#include <hip/hip_runtime.h>
#include <hip/hip_bf16.h>
#include <math.h>

#define HIDDEN 3584
#define NHEADS 28
#define NKV 4
#define HDIM 128
#define BB 2
#define SS 1024
#define CC 3072
#define TT 4096
#define BS 2048
#define NQ 3584
#define GROUPS 7
#define SCALE 0.08838834764831845f
#define QSCALE (SCALE * 1.44269504088896f)   /* fold log2(e) into q */
#define NT (HIDDEN / 32)   /* 112 K-steps */
#define SM_OFF2 23.0831206542234f            /* 16 * log2(e) */

typedef unsigned short u16;
typedef __attribute__((ext_vector_type(4))) unsigned short u16x4;
typedef __attribute__((ext_vector_type(8))) unsigned short u16x8;
typedef __attribute__((ext_vector_type(8))) short s16x8;
typedef __attribute__((ext_vector_type(4))) float f32x4;

__device__ inline u16 f2bf(float x) {
  union { float f; unsigned int u; } v; v.f = x;
  unsigned int r = v.u + 0x7FFFu + ((v.u >> 16) & 1u);
  return (u16)(r >> 16);
}
__device__ inline float bf2f(u16 u) {
  union { unsigned int i; float f; } v; v.i = ((unsigned int)u) << 16;
  return v.f;
}
__device__ inline unsigned int cvtpk(float lo, float hi) {
  unsigned int r;
  asm("v_cvt_pk_bf16_f32 %0, %1, %2" : "=v"(r) : "v"(lo), "v"(hi));
  return r;
}

// ---- cache copy: f32 passthrough + bf16 K + bf16 V-transposed -------------
__global__ __launch_bounds__(256) void copy_cache_kernel(
    const float4* __restrict__ kc, const float4* __restrict__ vc,
    float4* __restrict__ nk, float4* __restrict__ nv,
    u16* __restrict__ kbf, u16* __restrict__ vbft) {
  __shared__ u16 Tr[128][72];
  const int bh = blockIdx.y;     // 0..7 (b*4+hkv)
  const int t0 = blockIdx.x * 64;
  const int tid = threadIdx.x;
  #pragma unroll
  for (int i = 0; i < 8; ++i) {
    int idx = i * 256 + tid;          // 0..2047
    int r = idx >> 5, c = idx & 31;   // t-row, d-float4-chunk
    size_t src = ((size_t)bh * CC + t0 + r) * 32 + c;
    size_t dst = ((size_t)bh * TT + t0 + r) * 32 + c;
    float4 k4 = kc[src], v4 = vc[src];
    nk[dst] = k4; nv[dst] = v4;
    u16x4 kb; kb[0] = f2bf(k4.x); kb[1] = f2bf(k4.y); kb[2] = f2bf(k4.z); kb[3] = f2bf(k4.w);
    *(u16x4*)(kbf + dst * 4) = kb;
    Tr[c * 4 + 0][r] = f2bf(v4.x);
    Tr[c * 4 + 1][r] = f2bf(v4.y);
    Tr[c * 4 + 2][r] = f2bf(v4.z);
    Tr[c * 4 + 3][r] = f2bf(v4.w);
  }
  __syncthreads();
  const int d = tid >> 1, half = tid & 1;
  const size_t obase = ((size_t)bh * 128 + d) * (size_t)TT + t0 + half * 32;
  #pragma unroll
  for (int i = 0; i < 4; ++i) {
    u16x8 v = *(const u16x8*)&Tr[d][half * 32 + i * 8];
    *(u16x8*)(vbft + obase + i * 8) = v;
  }
}

// ---- f32 -> bf16 conversion (hidden_states / weights) ---------------------
__global__ __launch_bounds__(256) void cvt_bf16_kernel(
    const float4* __restrict__ src, u16* __restrict__ dst, int n4) {
  int i = blockIdx.x * 256 + threadIdx.x;
  if (i < n4) {
    float4 v = src[i];
    u16x4 o; o[0] = f2bf(v.x); o[1] = f2bf(v.y); o[2] = f2bf(v.z); o[3] = f2bf(v.w);
    *(u16x4*)(dst + (size_t)i * 4) = o;
  }
}

// ============================================================================
// FAST PATH GEMMs: m97-style, A and B both bf16 via global_load_lds
// ============================================================================
__global__ __launch_bounds__(256) void gemm_qkv_bf_kernel(
    const u16* __restrict__ hbf, const u16* __restrict__ wbf,
    const float* __restrict__ qb, const float* __restrict__ kb,
    const float* __restrict__ vb, const int* __restrict__ pos,
    u16* __restrict__ qbf, float* __restrict__ nk, float* __restrict__ nv,
    u16* __restrict__ kbf, u16* __restrict__ vbft) {
  __shared__ u16 Ab[2][128 * 32];
  __shared__ u16 Bb[2][128 * 32];
  const int tid = threadIdx.x;
  const int w = tid >> 6, lane = tid & 63, lr = lane & 15, lg = lane >> 4;
  const int m0 = blockIdx.y * 128, n0 = blockIdx.x * 128;

  const bool isq = (n0 < NQ);
  const bool isk = (!isq) && (n0 < NQ + 512);
  const float* bias;
  if (isq)      bias = qb + n0;
  else if (isk) bias = kb + (n0 - NQ);
  else          bias = vb + (n0 - NQ - 512);

  f32x4 acc[2][8];
  #pragma unroll
  for (int f = 0; f < 2; ++f)
    #pragma unroll
    for (int n = 0; n < 8; ++n) acc[f][n] = (f32x4){0.f, 0.f, 0.f, 0.f};

  auto stageAB = [&](int buf, int k0) {
    #pragma unroll
    for (int i = 0; i < 2; ++i) {
      int ci = w * 128 + i * 64 + lane;
      int row = ci >> 2, c = ci & 3;
      __builtin_amdgcn_global_load_lds(
          (const __attribute__((address_space(1))) void*)(hbf + (size_t)(m0 + row) * HIDDEN + k0 + c * 8),
          (__attribute__((address_space(3))) void*)(&Ab[buf][(w * 128 + i * 64) * 8]),
          16, 0, 0);
      __builtin_amdgcn_global_load_lds(
          (const __attribute__((address_space(1))) void*)(wbf + (size_t)(n0 + row) * HIDDEN + k0 + c * 8),
          (__attribute__((address_space(3))) void*)(&Bb[buf][(w * 128 + i * 64) * 8]),
          16, 0, 0);
    }
  };

  stageAB(0, 0);
  __syncthreads();

  for (int kt = 0; kt < NT; ++kt) {
    const int cur = kt & 1;
    if (kt + 1 < NT) stageAB(cur ^ 1, (kt + 1) * 32);
    s16x8 af[2];
    af[0] = *(const s16x8*)&Ab[cur][(w * 32 + lr) * 32 + lg * 8];
    af[1] = *(const s16x8*)&Ab[cur][(w * 32 + 16 + lr) * 32 + lg * 8];
    #pragma unroll
    for (int n = 0; n < 8; ++n) {
      const s16x8 bf_ = *(const s16x8*)&Bb[cur][(n * 16 + lr) * 32 + lg * 8];
      acc[0][n] = __builtin_amdgcn_mfma_f32_16x16x32_bf16(af[0], bf_, acc[0][n], 0, 0, 0);
      acc[1][n] = __builtin_amdgcn_mfma_f32_16x16x32_bf16(af[1], bf_, acc[1][n], 0, 0, 0);
    }
    __syncthreads();
  }

  float bias_v[8];
  #pragma unroll
  for (int n = 0; n < 8; ++n) bias_v[n] = bias[n * 16 + lr];
  float invf[4];
  if (isq || isk) {
    #pragma unroll
    for (int n = 0; n < 4; ++n)
      invf[n] = __expf(-(float)(n * 16 + lr) * 0.21586735246819178f); // ln(1e6)/64
  }
  const int kvh = isq ? 0 : ((isk ? (n0 - NQ) : (n0 - NQ - 512)) >> 7);

  #pragma unroll
  for (int f = 0; f < 2; ++f)
    #pragma unroll
    for (int reg = 0; reg < 4; ++reg) {
      int m = m0 + w * 32 + f * 16 + lg * 4 + reg;
      float y[8];
      #pragma unroll
      for (int n = 0; n < 8; ++n) y[n] = acc[f][n][reg] + bias_v[n];
      if (isq || isk) {
        float p = (float)pos[m];
        #pragma unroll
        for (int n = 0; n < 4; ++n) {
          float sA, cA;
          __sincosf(p * invf[n], &sA, &cA);
          float lo = y[n], hi = y[n + 4];
          y[n]     = lo * cA - hi * sA;
          y[n + 4] = hi * cA + lo * sA;
        }
      }
      if (isq) {
        u16* dst = qbf + (size_t)m * NQ + n0;
        #pragma unroll
        for (int n = 0; n < 8; ++n) dst[n * 16 + lr] = f2bf(y[n] * QSCALE);
      } else {
        int b_ = m >> 10, s_ = m & 1023;
        size_t rowoff = ((size_t)(b_ * NKV + kvh) * TT + CC + s_) * HDIM;
        if (isk) {
          #pragma unroll
          for (int n = 0; n < 8; ++n) {
            nk[rowoff + n * 16 + lr]  = y[n];
            kbf[rowoff + n * 16 + lr] = f2bf(y[n]);
          }
        } else {
          size_t vb0 = (size_t)(b_ * NKV + kvh) * 128;
          #pragma unroll
          for (int n = 0; n < 8; ++n) {
            nv[rowoff + n * 16 + lr] = y[n];
            vbft[(vb0 + n * 16 + lr) * (size_t)TT + CC + s_] = f2bf(y[n]);
          }
        }
      }
    }
}

__global__ __launch_bounds__(256) void gemm_out_bf_kernel(
    const u16* __restrict__ Abf, const u16* __restrict__ Wbf,
    float* __restrict__ Y) {
  __shared__ u16 Ab[2][128 * 32];
  __shared__ u16 Bb[2][128 * 32];
  const int tid = threadIdx.x;
  const int w = tid >> 6, lane = tid & 63, lr = lane & 15, lg = lane >> 4;
  const int m0 = blockIdx.y * 128, n0 = blockIdx.x * 128;

  f32x4 acc[2][8];
  #pragma unroll
  for (int f = 0; f < 2; ++f)
    #pragma unroll
    for (int n = 0; n < 8; ++n) acc[f][n] = (f32x4){0.f, 0.f, 0.f, 0.f};

  auto stageAB = [&](int buf, int k0) {
    #pragma unroll
    for (int i = 0; i < 2; ++i) {
      int ci = w * 128 + i * 64 + lane;
      int row = ci >> 2, c = ci & 3;
      __builtin_amdgcn_global_load_lds(
          (const __attribute__((address_space(1))) void*)(Abf + (size_t)(m0 + row) * HIDDEN + k0 + c * 8),
          (__attribute__((address_space(3))) void*)(&Ab[buf][(w * 128 + i * 64) * 8]),
          16, 0, 0);
      __builtin_amdgcn_global_load_lds(
          (const __attribute__((address_space(1))) void*)(Wbf + (size_t)(n0 + row) * HIDDEN + k0 + c * 8),
          (__attribute__((address_space(3))) void*)(&Bb[buf][(w * 128 + i * 64) * 8]),
          16, 0, 0);
    }
  };

  stageAB(0, 0);
  __syncthreads();

  for (int kt = 0; kt < NT; ++kt) {
    const int cur = kt & 1;
    if (kt + 1 < NT) stageAB(cur ^ 1, (kt + 1) * 32);
    s16x8 af[2];
    af[0] = *(const s16x8*)&Ab[cur][(w * 32 + lr) * 32 + lg * 8];
    af[1] = *(const s16x8*)&Ab[cur][(w * 32 + 16 + lr) * 32 + lg * 8];
    #pragma unroll
    for (int n = 0; n < 8; ++n) {
      const s16x8 bf_ = *(const s16x8*)&Bb[cur][(n * 16 + lr) * 32 + lg * 8];
      acc[0][n] = __builtin_amdgcn_mfma_f32_16x16x32_bf16(af[0], bf_, acc[0][n], 0, 0, 0);
      acc[1][n] = __builtin_amdgcn_mfma_f32_16x16x32_bf16(af[1], bf_, acc[1][n], 0, 0, 0);
    }
    __syncthreads();
  }

  #pragma unroll
  for (int f = 0; f < 2; ++f)
    #pragma unroll
    for (int reg = 0; reg < 4; ++reg) {
      int m = m0 + w * 32 + f * 16 + lg * 4 + reg;
      float* dst = Y + (size_t)m * NQ + n0;
      #pragma unroll
      for (int n = 0; n < 8; ++n) dst[n * 16 + lr] = acc[f][n][reg];
    }
}

// ============================================================================
// FALLBACK GEMMs (R7-proven): f32 weights reg-staged
// ============================================================================
__global__ __launch_bounds__(256) void gemm_qkv_kernel(
    const u16* __restrict__ hbf,
    const float* __restrict__ qw, const float* __restrict__ qb,
    const float* __restrict__ kw, const float* __restrict__ kb,
    const float* __restrict__ vw, const float* __restrict__ vb,
    const int* __restrict__ pos,
    u16* __restrict__ qbf, float* __restrict__ nk, float* __restrict__ nv,
    u16* __restrict__ kbf, u16* __restrict__ vbft) {
  __shared__ u16 Ab[2][128 * 32];
  __shared__ u16 Bb[2][128 * 32];
  const int tid = threadIdx.x;
  const int w = tid >> 6, lane = tid & 63, lr = lane & 15, lg = lane >> 4;
  const int m0 = blockIdx.y * 128, n0 = blockIdx.x * 128;

  const bool isq = (n0 < NQ);
  const bool isk = (!isq) && (n0 < NQ + 512);
  const float* Wb; const float* bias;
  if (isq)      { Wb = qw + (size_t)n0 * HIDDEN;          bias = qb + n0; }
  else if (isk) { Wb = kw + (size_t)(n0 - NQ) * HIDDEN;   bias = kb + (n0 - NQ); }
  else          { Wb = vw + (size_t)(n0 - NQ - 512) * HIDDEN; bias = vb + (n0 - NQ - 512); }

  f32x4 acc[2][8];
  #pragma unroll
  for (int f = 0; f < 2; ++f)
    #pragma unroll
    for (int n = 0; n < 8; ++n) acc[f][n] = (f32x4){0.f, 0.f, 0.f, 0.f};

  const int br = tid >> 1, bkh = (tid & 1) * 16;
  const float* Bsrc = Wb + (size_t)br * HIDDEN + bkh;

  auto stageA = [&](int buf, int k0) {
    #pragma unroll
    for (int i = 0; i < 2; ++i) {
      int ci = w * 128 + i * 64 + lane;
      int row = ci >> 2, c = ci & 3;
      __builtin_amdgcn_global_load_lds(
          (const __attribute__((address_space(1))) void*)(hbf + (size_t)(m0 + row) * HIDDEN + k0 + c * 8),
          (__attribute__((address_space(3))) void*)(&Ab[buf][(w * 128 + i * 64) * 8]),
          16, 0, 0);
    }
  };

  float4 fB[4];
  auto loadB = [&](int k0) {
    #pragma unroll
    for (int j = 0; j < 4; ++j) fB[j] = *(const float4*)(Bsrc + k0 + j * 4);
  };
  auto writeB = [&](int buf) {
    unsigned int pk[8];
    pk[0] = cvtpk(fB[0].x, fB[0].y); pk[1] = cvtpk(fB[0].z, fB[0].w);
    pk[2] = cvtpk(fB[1].x, fB[1].y); pk[3] = cvtpk(fB[1].z, fB[1].w);
    pk[4] = cvtpk(fB[2].x, fB[2].y); pk[5] = cvtpk(fB[2].z, fB[2].w);
    pk[6] = cvtpk(fB[3].x, fB[3].y); pk[7] = cvtpk(fB[3].z, fB[3].w);
    *(uint4*)&Bb[buf][br * 32 + bkh]     = make_uint4(pk[0], pk[1], pk[2], pk[3]);
    *(uint4*)&Bb[buf][br * 32 + bkh + 8] = make_uint4(pk[4], pk[5], pk[6], pk[7]);
  };

  stageA(0, 0); loadB(0); writeB(0);
  __syncthreads();

  for (int kt = 0; kt < NT; ++kt) {
    const int cur = kt & 1;
    if (kt + 1 < NT) { stageA(cur ^ 1, (kt + 1) * 32); loadB((kt + 1) * 32); }
    s16x8 af[2];
    af[0] = *(const s16x8*)&Ab[cur][(w * 32 + lr) * 32 + lg * 8];
    af[1] = *(const s16x8*)&Ab[cur][(w * 32 + 16 + lr) * 32 + lg * 8];
    #pragma unroll
    for (int n = 0; n < 8; ++n) {
      const s16x8 bf_ = *(const s16x8*)&Bb[cur][(n * 16 + lr) * 32 + lg * 8];
      acc[0][n] = __builtin_amdgcn_mfma_f32_16x16x32_bf16(af[0], bf_, acc[0][n], 0, 0, 0);
      acc[1][n] = __builtin_amdgcn_mfma_f32_16x16x32_bf16(af[1], bf_, acc[1][n], 0, 0, 0);
    }
    if (kt + 1 < NT) writeB(cur ^ 1);
    __syncthreads();
  }

  float bias_v[8];
  #pragma unroll
  for (int n = 0; n < 8; ++n) bias_v[n] = bias[n * 16 + lr];
  float invf[4];
  if (isq || isk) {
    #pragma unroll
    for (int n = 0; n < 4; ++n)
      invf[n] = __expf(-(float)(n * 16 + lr) * 0.21586735246819178f);
  }
  const int kvh = isq ? 0 : ((isk ? (n0 - NQ) : (n0 - NQ - 512)) >> 7);

  #pragma unroll
  for (int f = 0; f < 2; ++f)
    #pragma unroll
    for (int reg = 0; reg < 4; ++reg) {
      int m = m0 + w * 32 + f * 16 + lg * 4 + reg;
      float y[8];
      #pragma unroll
      for (int n = 0; n < 8; ++n) y[n] = acc[f][n][reg] + bias_v[n];
      if (isq || isk) {
        float p = (float)pos[m];
        #pragma unroll
        for (int n = 0; n < 4; ++n) {
          float sA, cA;
          __sincosf(p * invf[n], &sA, &cA);
          float lo = y[n], hi = y[n + 4];
          y[n]     = lo * cA - hi * sA;
          y[n + 4] = hi * cA + lo * sA;
        }
      }
      if (isq) {
        u16* dst = qbf + (size_t)m * NQ + n0;
        #pragma unroll
        for (int n = 0; n < 8; ++n) dst[n * 16 + lr] = f2bf(y[n] * QSCALE);
      } else {
        int b_ = m >> 10, s_ = m & 1023;
        size_t rowoff = ((size_t)(b_ * NKV + kvh) * TT + CC + s_) * HDIM;
        if (isk) {
          #pragma unroll
          for (int n = 0; n < 8; ++n) {
            nk[rowoff + n * 16 + lr]  = y[n];
            kbf[rowoff + n * 16 + lr] = f2bf(y[n]);
          }
        } else {
          size_t vb0 = (size_t)(b_ * NKV + kvh) * 128;
          #pragma unroll
          for (int n = 0; n < 8; ++n) {
            nv[rowoff + n * 16 + lr] = y[n];
            vbft[(vb0 + n * 16 + lr) * (size_t)TT + CC + s_] = f2bf(y[n]);
          }
        }
      }
    }
}

__global__ __launch_bounds__(256) void gemm_out_kernel(
    const u16* __restrict__ Abf, const float* __restrict__ W,
    float* __restrict__ Y) {
  __shared__ u16 Ab[2][128 * 32];
  __shared__ u16 Bb[2][128 * 32];
  const int tid = threadIdx.x;
  const int w = tid >> 6, lane = tid & 63, lr = lane & 15, lg = lane >> 4;
  const int m0 = blockIdx.y * 128, n0 = blockIdx.x * 128;

  f32x4 acc[2][8];
  #pragma unroll
  for (int f = 0; f < 2; ++f)
    #pragma unroll
    for (int n = 0; n < 8; ++n) acc[f][n] = (f32x4){0.f, 0.f, 0.f, 0.f};

  const int br = tid >> 1, bkh = (tid & 1) * 16;
  const float* Bsrc = W + (size_t)(n0 + br) * HIDDEN + bkh;

  auto stageA = [&](int buf, int k0) {
    #pragma unroll
    for (int i = 0; i < 2; ++i) {
      int ci = w * 128 + i * 64 + lane;
      int row = ci >> 2, c = ci & 3;
      __builtin_amdgcn_global_load_lds(
          (const __attribute__((address_space(1))) void*)(Abf + (size_t)(m0 + row) * HIDDEN + k0 + c * 8),
          (__attribute__((address_space(3))) void*)(&Ab[buf][(w * 128 + i * 64) * 8]),
          16, 0, 0);
    }
  };

  float4 fB[4];
  auto loadB = [&](int k0) {
    #pragma unroll
    for (int j = 0; j < 4; ++j) fB[j] = *(const float4*)(Bsrc + k0 + j * 4);
  };
  auto writeB = [&](int buf) {
    unsigned int pk[8];
    pk[0] = cvtpk(fB[0].x, fB[0].y); pk[1] = cvtpk(fB[0].z, fB[0].w);
    pk[2] = cvtpk(fB[1].x, fB[1].y); pk[3] = cvtpk(fB[1].z, fB[1].w);
    pk[4] = cvtpk(fB[2].x, fB[2].y); pk[5] = cvtpk(fB[2].z, fB[2].w);
    pk[6] = cvtpk(fB[3].x, fB[3].y); pk[7] = cvtpk(fB[3].z, fB[3].w);
    *(uint4*)&Bb[buf][br * 32 + bkh]     = make_uint4(pk[0], pk[1], pk[2], pk[3]);
    *(uint4*)&Bb[buf][br * 32 + bkh + 8] = make_uint4(pk[4], pk[5], pk[6], pk[7]);
  };

  stageA(0, 0); loadB(0); writeB(0);
  __syncthreads();

  for (int kt = 0; kt < NT; ++kt) {
    const int cur = kt & 1;
    if (kt + 1 < NT) { stageA(cur ^ 1, (kt + 1) * 32); loadB((kt + 1) * 32); }
    s16x8 af[2];
    af[0] = *(const s16x8*)&Ab[cur][(w * 32 + lr) * 32 + lg * 8];
    af[1] = *(const s16x8*)&Ab[cur][(w * 32 + 16 + lr) * 32 + lg * 8];
    #pragma unroll
    for (int n = 0; n < 8; ++n) {
      const s16x8 bf_ = *(const s16x8*)&Bb[cur][(n * 16 + lr) * 32 + lg * 8];
      acc[0][n] = __builtin_amdgcn_mfma_f32_16x16x32_bf16(af[0], bf_, acc[0][n], 0, 0, 0);
      acc[1][n] = __builtin_amdgcn_mfma_f32_16x16x32_bf16(af[1], bf_, acc[1][n], 0, 0, 0);
    }
    if (kt + 1 < NT) writeB(cur ^ 1);
    __syncthreads();
  }

  #pragma unroll
  for (int f = 0; f < 2; ++f)
    #pragma unroll
    for (int reg = 0; reg < 4; ++reg) {
      int m = m0 + w * 32 + f * 16 + lg * 4 + reg;
      float* dst = Y + (size_t)m * NQ + n0;
      #pragma unroll
      for (int n = 0; n < 8; ++n) dst[n * 16 + lr] = acc[f][n][reg];
    }
}

// ---- MFMA flash attention: 8 waves = 2 quads, KV-split, BKV=32, dbuf ------
// K rows kv-permuted in LDS so QK^T C-frag == PV A-frag (P stays in regs).
// V chunk-swizzled (f(row) = (row>>1)&3) -> PV ds_read_b128 is 2-way (free).
__global__ __launch_bounds__(512, 2) void attn_kernel(
    const u16* __restrict__ qbf, const u16* __restrict__ kbf,
    const u16* __restrict__ vbft, u16* __restrict__ aout) {
  __shared__ __align__(16) u16 SMEM[34816];  // 68 KB

  const int orig = blockIdx.x;              // 224 = 8 XCD-chunks of 28
  const int swzb = (orig & 7) * 28 + (orig >> 3);
  const int g    = swzb / 28;
  const int ii   = swzb % 28;
  const int b    = g >> 2;
  const int hkv  = g & 3;
  const int h    = hkv * GROUPS + (ii >> 2);
  const int q0   = (ii & 3) * 256;

  const int tid  = threadIdx.x;
  const int w    = tid >> 6;
  const int quad = w >> 2;
  const int wq   = w & 3;
  const int lane = tid & 63;
  const int lr   = lane & 15;
  const int lg   = lane >> 4;
  const int qw0  = q0 + wq * 64;

  s16x8 qf[4][4];
  #pragma unroll
  for (int fq = 0; fq < 4; ++fq) {
    const u16* qp = qbf + (size_t)(b * SS + qw0 + fq * 16 + lr) * NQ + h * HDIM + lg * 8;
    #pragma unroll
    for (int kk = 0; kk < 4; ++kk) qf[fq][kk] = *(const s16x8*)(qp + kk * 32);
  }

  const size_t bh = (size_t)(b * NKV + hkv);
  const u16* kB = kbf  + bh * (size_t)TT * HDIM;
  const u16* vB = vbft + bh * (size_t)HDIM * TT;

  f32x4 oacc[4][8];
  #pragma unroll
  for (int fq = 0; fq < 4; ++fq)
    #pragma unroll
    for (int n = 0; n < 8; ++n) oacc[fq][n] = (f32x4){0.f, 0.f, 0.f, 0.f};
  float lsum[4] = {0.f, 0.f, 0.f, 0.f};

  u16* Ksq = SMEM + quad * 8192;
  u16* Vsq = SMEM + 16384 + quad * 8192;

  auto stage = [&](int buf, int kt) {
    #pragma unroll
    for (int i = 0; i < 2; ++i) {
      int ci = (wq * 2 + i) * 64 + lane;
      // K: dest slot s = ci>>4; source row kv = sigma^-1(s)
      int s = ci >> 4, kc_ = ci & 15;
      int kv = (((s >> 3) & 1) << 4) | (((s >> 2) & 1) << 3)
             | (((s >> 4) & 1) << 2) | (s & 3);
      const u16* ksrc = kB + (size_t)(kt * 32 + kv) * HDIM + ((kc_ ^ (s & 7)) * 8);
      __builtin_amdgcn_global_load_lds(
          (const __attribute__((address_space(1))) void*)ksrc,
          (__attribute__((address_space(3))) void*)(Ksq + buf * 4096 + (wq * 2 + i) * 512),
          16, 0, 0);
      // V: dest (row vd, chunk vc_) holds source chunk vc_ ^ ((vd>>1)&3)
      int vd = ci >> 2, vc_ = ci & 3;
      const u16* vsrc = vB + (size_t)vd * TT + kt * 32 + ((vc_ ^ ((vd >> 1) & 3)) * 8);
      __builtin_amdgcn_global_load_lds(
          (const __attribute__((address_space(1))) void*)vsrc,
          (__attribute__((address_space(3))) void*)(Vsq + buf * 4096 + (wq * 2 + i) * 512),
          16, 0, 0);
    }
  };

  const int tbase = quad * 64;
  stage(0, tbase);
  __syncthreads();

  for (int it = 0; it < 64; ++it) {
    const int cur = it & 1;
    if (it + 1 < 64) stage(cur ^ 1, tbase + it + 1);

    // ---- QK^T (swapped): D col = q, rows = permuted kv slots ----
    f32x4 sacc[4][2];
    #pragma unroll
    for (int fq = 0; fq < 4; ++fq)
      #pragma unroll
      for (int n = 0; n < 2; ++n) sacc[fq][n] = (f32x4){0.f, 0.f, 0.f, 0.f};
    __builtin_amdgcn_s_setprio(1);
    #pragma unroll
    for (int kk = 0; kk < 4; ++kk) {
      #pragma unroll
      for (int n = 0; n < 2; ++n) {
        int row = n * 16 + lr;
        const s16x8 kf = *(const s16x8*)&Ksq[cur * 4096 + row * 128 + (((kk * 4 + lg) ^ (row & 7)) * 8)];
        #pragma unroll
        for (int fq = 0; fq < 4; ++fq)
          sacc[fq][n] = __builtin_amdgcn_mfma_f32_16x16x32_bf16(kf, qf[fq][kk], sacc[fq][n], 0, 0, 0);
      }
    }
    __builtin_amdgcn_s_setprio(0);

    // ---- fixed-offset softmax via exp2 (log2e folded into q scale) -------
    s16x8 pa[4];
    #pragma unroll
    for (int fq = 0; fq < 4; ++fq) {
      float p00 = exp2f(sacc[fq][0][0] - SM_OFF2);
      float p01 = exp2f(sacc[fq][0][1] - SM_OFF2);
      float p02 = exp2f(sacc[fq][0][2] - SM_OFF2);
      float p03 = exp2f(sacc[fq][0][3] - SM_OFF2);
      float p10 = exp2f(sacc[fq][1][0] - SM_OFF2);
      float p11 = exp2f(sacc[fq][1][1] - SM_OFF2);
      float p12 = exp2f(sacc[fq][1][2] - SM_OFF2);
      float p13 = exp2f(sacc[fq][1][3] - SM_OFF2);
      lsum[fq] += ((p00 + p01) + (p02 + p03)) + ((p10 + p11) + (p12 + p13));
      uint4 pk4 = make_uint4(cvtpk(p00, p01), cvtpk(p02, p03),
                             cvtpk(p10, p11), cvtpk(p12, p13));
      pa[fq] = *(s16x8*)&pk4;
    }

    // ---- PV: O[q][d] += P[q][kv] * V^T[d][kv], k = 32 ----
    __builtin_amdgcn_s_setprio(1);
    #pragma unroll
    for (int n = 0; n < 8; ++n) {
      int row = n * 16 + lr;
      const s16x8 vf = *(const s16x8*)&Vsq[cur * 4096 + row * 32 + ((lg ^ ((row >> 1) & 3)) * 8)];
      #pragma unroll
      for (int fq = 0; fq < 4; ++fq)
        oacc[fq][n] = __builtin_amdgcn_mfma_f32_16x16x32_bf16(pa[fq], vf, oacc[fq][n], 0, 0, 0);
    }
    __builtin_amdgcn_s_setprio(0);

    __syncthreads();   // full drain: next-tile loads landed; all waves done with cur
  }

  // ---- combine quads (exact: partials additive), then finalize ----
  f32x4* OX = (f32x4*)SMEM;              // 64 KB (Ks+Vs dead)
  float* LX = (float*)(SMEM + 32768);    // 4 KB tail
  #pragma unroll
  for (int half = 0; half < 2; ++half) {
    if (quad == 1) {
      #pragma unroll
      for (int fp = 0; fp < 2; ++fp) {
        int fq = half * 2 + fp;
        #pragma unroll
        for (int n = 0; n < 8; ++n)
          OX[(fp * 8 + n) * 256 + wq * 64 + lane] = oacc[fq][n];
      }
      if (half == 0) {
        #pragma unroll
        for (int fq = 0; fq < 4; ++fq) LX[fq * 256 + wq * 64 + lane] = lsum[fq];
      }
    }
    __syncthreads();
    if (quad == 0) {
      #pragma unroll
      for (int fp = 0; fp < 2; ++fp) {
        int fq = half * 2 + fp;
        #pragma unroll
        for (int n = 0; n < 8; ++n) {
          f32x4 v = OX[(fp * 8 + n) * 256 + wq * 64 + lane];
          oacc[fq][n] += v;
        }
      }
      if (half == 0) {
        #pragma unroll
        for (int fq = 0; fq < 4; ++fq) lsum[fq] += LX[fq * 256 + wq * 64 + lane];
      }
    }
    __syncthreads();
  }

  if (quad == 0) {
    #pragma unroll
    for (int fq = 0; fq < 4; ++fq) {
      float s = lsum[fq];
      s += __shfl_xor(s, 16);
      s += __shfl_xor(s, 32);            // every lane: total for q = lr
      #pragma unroll
      for (int reg = 0; reg < 4; ++reg) {
        int qrow = lg * 4 + reg;
        float invl = 1.f / __shfl(s, qrow);   // total for q = qrow
        u16* orow = aout + (size_t)(b * SS + qw0 + fq * 16 + qrow) * NQ + h * HDIM;
        #pragma unroll
        for (int n = 0; n < 8; ++n)
          orow[n * 16 + lr] = f2bf(oacc[fq][n][reg] * invl);
      }
    }
  }
}

extern "C" void kernel_launch(void* const* d_in, const int* in_sizes, int n_in,
                              void* d_out, int out_size, void* d_ws, size_t ws_size,
                              hipStream_t stream) {
  const int*   positions = (const int*)d_in[0];
  const float* hidden    = (const float*)d_in[1];
  const float* kcache    = (const float*)d_in[2];
  const float* vcache    = (const float*)d_in[3];
  const float* qw = (const float*)d_in[5];
  const float* qb = (const float*)d_in[6];
  const float* kw = (const float*)d_in[7];
  const float* kb = (const float*)d_in[8];
  const float* vw = (const float*)d_in[9];
  const float* vb = (const float*)d_in[10];
  const float* ow = (const float*)d_in[11];

  float* out = (float*)d_out;                        // [2048][3584]
  float* nk  = out + (size_t)BS * NQ;                // [2,4,4096,128] f32
  float* nv  = nk + (size_t)BB * NKV * TT * HDIM;

  u16* qbf  = (u16*)d_ws;                            // [2048][3584]
  u16* kbf  = qbf + (size_t)BS * NQ;                 // [8][4096][128]
  u16* vbft = kbf + (size_t)BB * NKV * TT * HDIM;    // [8][128][4096]
  u16* hbf  = vbft + (size_t)BB * NKV * HDIM * TT;   // [2048][3584] (aliased: aws)
  u16* aws  = hbf;
  u16* wqkv = hbf + (size_t)BS * NQ;                 // [4608][3584] bf16 (fast path)
  u16* owbf = wqkv;                                  // [3584][3584] bf16, aliases wqkv

  const size_t fast_need = ((size_t)BS * NQ * 2 + (size_t)BB * NKV * TT * HDIM * 2
                            + (size_t)(NQ + 1024) * HIDDEN) * sizeof(u16);
  const bool fast = ws_size >= fast_need;

  copy_cache_kernel<<<dim3(CC / 64, BB * NKV), 256, 0, stream>>>(
      (const float4*)kcache, (const float4*)vcache,
      (float4*)nk, (float4*)nv, kbf, vbft);
  cvt_bf16_kernel<<<(BS * HIDDEN / 4 + 255) / 256, 256, 0, stream>>>(
      (const float4*)hidden, hbf, BS * HIDDEN / 4);

  if (fast) {
    cvt_bf16_kernel<<<(NQ * HIDDEN / 4 + 255) / 256, 256, 0, stream>>>(
        (const float4*)qw, wqkv, NQ * HIDDEN / 4);
    cvt_bf16_kernel<<<(512 * HIDDEN / 4 + 255) / 256, 256, 0, stream>>>(
        (const float4*)kw, wqkv + (size_t)NQ * HIDDEN, 512 * HIDDEN / 4);
    cvt_bf16_kernel<<<(512 * HIDDEN / 4 + 255) / 256, 256, 0, stream>>>(
        (const float4*)vw, wqkv + (size_t)(NQ + 512) * HIDDEN, 512 * HIDDEN / 4);
    gemm_qkv_bf_kernel<<<dim3(36, 16), 256, 0, stream>>>(
        hbf, wqkv, qb, kb, vb, positions, qbf, nk, nv, kbf, vbft);
    cvt_bf16_kernel<<<(NQ * HIDDEN / 4 + 255) / 256, 256, 0, stream>>>(
        (const float4*)ow, owbf, NQ * HIDDEN / 4);
    attn_kernel<<<224, 512, 0, stream>>>(qbf, kbf, vbft, aws);
    gemm_out_bf_kernel<<<dim3(28, 16), 256, 0, stream>>>(aws, owbf, out);
  } else {
    gemm_qkv_kernel<<<dim3(36, 16), 256, 0, stream>>>(
        hbf, qw, qb, kw, kb, vw, vb, positions, qbf, nk, nv, kbf, vbft);
    attn_kernel<<<224, 512, 0, stream>>>(qbf, kbf, vbft, aws);
    gemm_out_kernel<<<dim3(28, 16), 256, 0, stream>>>(aws, ow, out);
  }
}

// Round 13
// 387.505 us; speedup vs baseline: 1.1381x; 1.1381x over previous
//
#include <hip/hip_runtime.h>
#include <hip/hip_bf16.h>
#include <math.h>

#define HIDDEN 3584
#define NHEADS 28
#define NKV 4
#define HDIM 128
#define BB 2
#define SS 1024
#define CC 3072
#define TT 4096
#define BS 2048
#define NQ 3584
#define GROUPS 7
#define SCALE 0.08838834764831845f
#define QSCALE (SCALE * 1.44269504088896f)   /* fold log2(e) into q */
#define NT (HIDDEN / 32)   /* 112 K-steps */
#define SM_OFF2 23.0831206542234f            /* 16 * log2(e) */

typedef unsigned short u16;
typedef __attribute__((ext_vector_type(4))) unsigned short u16x4;
typedef __attribute__((ext_vector_type(8))) unsigned short u16x8;
typedef __attribute__((ext_vector_type(8))) short s16x8;
typedef __attribute__((ext_vector_type(4))) float f32x4;

__device__ inline u16 f2bf(float x) {
  union { float f; unsigned int u; } v; v.f = x;
  unsigned int r = v.u + 0x7FFFu + ((v.u >> 16) & 1u);
  return (u16)(r >> 16);
}
__device__ inline float bf2f(u16 u) {
  union { unsigned int i; float f; } v; v.i = ((unsigned int)u) << 16;
  return v.f;
}
__device__ inline unsigned int cvtpk(float lo, float hi) {
  unsigned int r;
  asm("v_cvt_pk_bf16_f32 %0, %1, %2" : "=v"(r) : "v"(lo), "v"(hi));
  return r;
}
__device__ inline float exp2_raw(float x) {   // raw v_exp_f32: 2^x, 1 instr
  float r;
  asm("v_exp_f32 %0, %1" : "=v"(r) : "v"(x));
  return r;
}

// ---- cache copy: f32 passthrough + bf16 K + bf16 V-transposed -------------
__global__ __launch_bounds__(256) void copy_cache_kernel(
    const float4* __restrict__ kc, const float4* __restrict__ vc,
    float4* __restrict__ nk, float4* __restrict__ nv,
    u16* __restrict__ kbf, u16* __restrict__ vbft) {
  __shared__ u16 Tr[128][72];
  const int bh = blockIdx.y;     // 0..7 (b*4+hkv)
  const int t0 = blockIdx.x * 64;
  const int tid = threadIdx.x;
  #pragma unroll
  for (int i = 0; i < 8; ++i) {
    int idx = i * 256 + tid;          // 0..2047
    int r = idx >> 5, c = idx & 31;   // t-row, d-float4-chunk
    size_t src = ((size_t)bh * CC + t0 + r) * 32 + c;
    size_t dst = ((size_t)bh * TT + t0 + r) * 32 + c;
    float4 k4 = kc[src], v4 = vc[src];
    nk[dst] = k4; nv[dst] = v4;
    u16x4 kb; kb[0] = f2bf(k4.x); kb[1] = f2bf(k4.y); kb[2] = f2bf(k4.z); kb[3] = f2bf(k4.w);
    *(u16x4*)(kbf + dst * 4) = kb;
    Tr[c * 4 + 0][r] = f2bf(v4.x);
    Tr[c * 4 + 1][r] = f2bf(v4.y);
    Tr[c * 4 + 2][r] = f2bf(v4.z);
    Tr[c * 4 + 3][r] = f2bf(v4.w);
  }
  __syncthreads();
  const int d = tid >> 1, half = tid & 1;
  const size_t obase = ((size_t)bh * 128 + d) * (size_t)TT + t0 + half * 32;
  #pragma unroll
  for (int i = 0; i < 4; ++i) {
    u16x8 v = *(const u16x8*)&Tr[d][half * 32 + i * 8];
    *(u16x8*)(vbft + obase + i * 8) = v;
  }
}

// ---- f32 -> bf16 conversion (hidden_states / weights) ---------------------
__global__ __launch_bounds__(256) void cvt_bf16_kernel(
    const float4* __restrict__ src, u16* __restrict__ dst, int n4) {
  int i = blockIdx.x * 256 + threadIdx.x;
  if (i < n4) {
    float4 v = src[i];
    u16x4 o; o[0] = f2bf(v.x); o[1] = f2bf(v.y); o[2] = f2bf(v.z); o[3] = f2bf(v.w);
    *(u16x4*)(dst + (size_t)i * 4) = o;
  }
}

// ============================================================================
// FAST PATH GEMMs: m97-style, A and B both bf16 via global_load_lds
// ============================================================================
__global__ __launch_bounds__(256) void gemm_qkv_bf_kernel(
    const u16* __restrict__ hbf, const u16* __restrict__ wbf,
    const float* __restrict__ qb, const float* __restrict__ kb,
    const float* __restrict__ vb, const int* __restrict__ pos,
    u16* __restrict__ qbf, float* __restrict__ nk, float* __restrict__ nv,
    u16* __restrict__ kbf, u16* __restrict__ vbft) {
  __shared__ u16 Ab[2][128 * 32];
  __shared__ u16 Bb[2][128 * 32];
  const int tid = threadIdx.x;
  const int w = tid >> 6, lane = tid & 63, lr = lane & 15, lg = lane >> 4;
  const int m0 = blockIdx.y * 128, n0 = blockIdx.x * 128;

  const bool isq = (n0 < NQ);
  const bool isk = (!isq) && (n0 < NQ + 512);
  const float* bias;
  if (isq)      bias = qb + n0;
  else if (isk) bias = kb + (n0 - NQ);
  else          bias = vb + (n0 - NQ - 512);

  f32x4 acc[2][8];
  #pragma unroll
  for (int f = 0; f < 2; ++f)
    #pragma unroll
    for (int n = 0; n < 8; ++n) acc[f][n] = (f32x4){0.f, 0.f, 0.f, 0.f};

  auto stageAB = [&](int buf, int k0) {
    #pragma unroll
    for (int i = 0; i < 2; ++i) {
      int ci = w * 128 + i * 64 + lane;
      int row = ci >> 2, c = ci & 3;
      __builtin_amdgcn_global_load_lds(
          (const __attribute__((address_space(1))) void*)(hbf + (size_t)(m0 + row) * HIDDEN + k0 + c * 8),
          (__attribute__((address_space(3))) void*)(&Ab[buf][(w * 128 + i * 64) * 8]),
          16, 0, 0);
      __builtin_amdgcn_global_load_lds(
          (const __attribute__((address_space(1))) void*)(wbf + (size_t)(n0 + row) * HIDDEN + k0 + c * 8),
          (__attribute__((address_space(3))) void*)(&Bb[buf][(w * 128 + i * 64) * 8]),
          16, 0, 0);
    }
  };

  stageAB(0, 0);
  __syncthreads();

  for (int kt = 0; kt < NT; ++kt) {
    const int cur = kt & 1;
    if (kt + 1 < NT) stageAB(cur ^ 1, (kt + 1) * 32);
    s16x8 af[2];
    af[0] = *(const s16x8*)&Ab[cur][(w * 32 + lr) * 32 + lg * 8];
    af[1] = *(const s16x8*)&Ab[cur][(w * 32 + 16 + lr) * 32 + lg * 8];
    #pragma unroll
    for (int n = 0; n < 8; ++n) {
      const s16x8 bf_ = *(const s16x8*)&Bb[cur][(n * 16 + lr) * 32 + lg * 8];
      acc[0][n] = __builtin_amdgcn_mfma_f32_16x16x32_bf16(af[0], bf_, acc[0][n], 0, 0, 0);
      acc[1][n] = __builtin_amdgcn_mfma_f32_16x16x32_bf16(af[1], bf_, acc[1][n], 0, 0, 0);
    }
    __syncthreads();
  }

  float bias_v[8];
  #pragma unroll
  for (int n = 0; n < 8; ++n) bias_v[n] = bias[n * 16 + lr];
  float invf[4];
  if (isq || isk) {
    #pragma unroll
    for (int n = 0; n < 4; ++n)
      invf[n] = __expf(-(float)(n * 16 + lr) * 0.21586735246819178f); // ln(1e6)/64
  }
  const int kvh = isq ? 0 : ((isk ? (n0 - NQ) : (n0 - NQ - 512)) >> 7);

  #pragma unroll
  for (int f = 0; f < 2; ++f)
    #pragma unroll
    for (int reg = 0; reg < 4; ++reg) {
      int m = m0 + w * 32 + f * 16 + lg * 4 + reg;
      float y[8];
      #pragma unroll
      for (int n = 0; n < 8; ++n) y[n] = acc[f][n][reg] + bias_v[n];
      if (isq || isk) {
        float p = (float)pos[m];
        #pragma unroll
        for (int n = 0; n < 4; ++n) {
          float sA, cA;
          __sincosf(p * invf[n], &sA, &cA);
          float lo = y[n], hi = y[n + 4];
          y[n]     = lo * cA - hi * sA;
          y[n + 4] = hi * cA + lo * sA;
        }
      }
      if (isq) {
        u16* dst = qbf + (size_t)m * NQ + n0;
        #pragma unroll
        for (int n = 0; n < 8; ++n) dst[n * 16 + lr] = f2bf(y[n] * QSCALE);
      } else {
        int b_ = m >> 10, s_ = m & 1023;
        size_t rowoff = ((size_t)(b_ * NKV + kvh) * TT + CC + s_) * HDIM;
        if (isk) {
          #pragma unroll
          for (int n = 0; n < 8; ++n) {
            nk[rowoff + n * 16 + lr]  = y[n];
            kbf[rowoff + n * 16 + lr] = f2bf(y[n]);
          }
        } else {
          size_t vb0 = (size_t)(b_ * NKV + kvh) * 128;
          #pragma unroll
          for (int n = 0; n < 8; ++n) {
            nv[rowoff + n * 16 + lr] = y[n];
            vbft[(vb0 + n * 16 + lr) * (size_t)TT + CC + s_] = f2bf(y[n]);
          }
        }
      }
    }
}

__global__ __launch_bounds__(256) void gemm_out_bf_kernel(
    const u16* __restrict__ Abf, const u16* __restrict__ Wbf,
    float* __restrict__ Y) {
  __shared__ u16 Ab[2][128 * 32];
  __shared__ u16 Bb[2][128 * 32];
  const int tid = threadIdx.x;
  const int w = tid >> 6, lane = tid & 63, lr = lane & 15, lg = lane >> 4;
  const int m0 = blockIdx.y * 128, n0 = blockIdx.x * 128;

  f32x4 acc[2][8];
  #pragma unroll
  for (int f = 0; f < 2; ++f)
    #pragma unroll
    for (int n = 0; n < 8; ++n) acc[f][n] = (f32x4){0.f, 0.f, 0.f, 0.f};

  auto stageAB = [&](int buf, int k0) {
    #pragma unroll
    for (int i = 0; i < 2; ++i) {
      int ci = w * 128 + i * 64 + lane;
      int row = ci >> 2, c = ci & 3;
      __builtin_amdgcn_global_load_lds(
          (const __attribute__((address_space(1))) void*)(Abf + (size_t)(m0 + row) * HIDDEN + k0 + c * 8),
          (__attribute__((address_space(3))) void*)(&Ab[buf][(w * 128 + i * 64) * 8]),
          16, 0, 0);
      __builtin_amdgcn_global_load_lds(
          (const __attribute__((address_space(1))) void*)(Wbf + (size_t)(n0 + row) * HIDDEN + k0 + c * 8),
          (__attribute__((address_space(3))) void*)(&Bb[buf][(w * 128 + i * 64) * 8]),
          16, 0, 0);
    }
  };

  stageAB(0, 0);
  __syncthreads();

  for (int kt = 0; kt < NT; ++kt) {
    const int cur = kt & 1;
    if (kt + 1 < NT) stageAB(cur ^ 1, (kt + 1) * 32);
    s16x8 af[2];
    af[0] = *(const s16x8*)&Ab[cur][(w * 32 + lr) * 32 + lg * 8];
    af[1] = *(const s16x8*)&Ab[cur][(w * 32 + 16 + lr) * 32 + lg * 8];
    #pragma unroll
    for (int n = 0; n < 8; ++n) {
      const s16x8 bf_ = *(const s16x8*)&Bb[cur][(n * 16 + lr) * 32 + lg * 8];
      acc[0][n] = __builtin_amdgcn_mfma_f32_16x16x32_bf16(af[0], bf_, acc[0][n], 0, 0, 0);
      acc[1][n] = __builtin_amdgcn_mfma_f32_16x16x32_bf16(af[1], bf_, acc[1][n], 0, 0, 0);
    }
    __syncthreads();
  }

  #pragma unroll
  for (int f = 0; f < 2; ++f)
    #pragma unroll
    for (int reg = 0; reg < 4; ++reg) {
      int m = m0 + w * 32 + f * 16 + lg * 4 + reg;
      float* dst = Y + (size_t)m * NQ + n0;
      #pragma unroll
      for (int n = 0; n < 8; ++n) dst[n * 16 + lr] = acc[f][n][reg];
    }
}

// ============================================================================
// FALLBACK GEMMs (R7-proven): f32 weights reg-staged
// ============================================================================
__global__ __launch_bounds__(256) void gemm_qkv_kernel(
    const u16* __restrict__ hbf,
    const float* __restrict__ qw, const float* __restrict__ qb,
    const float* __restrict__ kw, const float* __restrict__ kb,
    const float* __restrict__ vw, const float* __restrict__ vb,
    const int* __restrict__ pos,
    u16* __restrict__ qbf, float* __restrict__ nk, float* __restrict__ nv,
    u16* __restrict__ kbf, u16* __restrict__ vbft) {
  __shared__ u16 Ab[2][128 * 32];
  __shared__ u16 Bb[2][128 * 32];
  const int tid = threadIdx.x;
  const int w = tid >> 6, lane = tid & 63, lr = lane & 15, lg = lane >> 4;
  const int m0 = blockIdx.y * 128, n0 = blockIdx.x * 128;

  const bool isq = (n0 < NQ);
  const bool isk = (!isq) && (n0 < NQ + 512);
  const float* Wb; const float* bias;
  if (isq)      { Wb = qw + (size_t)n0 * HIDDEN;          bias = qb + n0; }
  else if (isk) { Wb = kw + (size_t)(n0 - NQ) * HIDDEN;   bias = kb + (n0 - NQ); }
  else          { Wb = vw + (size_t)(n0 - NQ - 512) * HIDDEN; bias = vb + (n0 - NQ - 512); }

  f32x4 acc[2][8];
  #pragma unroll
  for (int f = 0; f < 2; ++f)
    #pragma unroll
    for (int n = 0; n < 8; ++n) acc[f][n] = (f32x4){0.f, 0.f, 0.f, 0.f};

  const int br = tid >> 1, bkh = (tid & 1) * 16;
  const float* Bsrc = Wb + (size_t)br * HIDDEN + bkh;

  auto stageA = [&](int buf, int k0) {
    #pragma unroll
    for (int i = 0; i < 2; ++i) {
      int ci = w * 128 + i * 64 + lane;
      int row = ci >> 2, c = ci & 3;
      __builtin_amdgcn_global_load_lds(
          (const __attribute__((address_space(1))) void*)(hbf + (size_t)(m0 + row) * HIDDEN + k0 + c * 8),
          (__attribute__((address_space(3))) void*)(&Ab[buf][(w * 128 + i * 64) * 8]),
          16, 0, 0);
    }
  };

  float4 fB[4];
  auto loadB = [&](int k0) {
    #pragma unroll
    for (int j = 0; j < 4; ++j) fB[j] = *(const float4*)(Bsrc + k0 + j * 4);
  };
  auto writeB = [&](int buf) {
    unsigned int pk[8];
    pk[0] = cvtpk(fB[0].x, fB[0].y); pk[1] = cvtpk(fB[0].z, fB[0].w);
    pk[2] = cvtpk(fB[1].x, fB[1].y); pk[3] = cvtpk(fB[1].z, fB[1].w);
    pk[4] = cvtpk(fB[2].x, fB[2].y); pk[5] = cvtpk(fB[2].z, fB[2].w);
    pk[6] = cvtpk(fB[3].x, fB[3].y); pk[7] = cvtpk(fB[3].z, fB[3].w);
    *(uint4*)&Bb[buf][br * 32 + bkh]     = make_uint4(pk[0], pk[1], pk[2], pk[3]);
    *(uint4*)&Bb[buf][br * 32 + bkh + 8] = make_uint4(pk[4], pk[5], pk[6], pk[7]);
  };

  stageA(0, 0); loadB(0); writeB(0);
  __syncthreads();

  for (int kt = 0; kt < NT; ++kt) {
    const int cur = kt & 1;
    if (kt + 1 < NT) { stageA(cur ^ 1, (kt + 1) * 32); loadB((kt + 1) * 32); }
    s16x8 af[2];
    af[0] = *(const s16x8*)&Ab[cur][(w * 32 + lr) * 32 + lg * 8];
    af[1] = *(const s16x8*)&Ab[cur][(w * 32 + 16 + lr) * 32 + lg * 8];
    #pragma unroll
    for (int n = 0; n < 8; ++n) {
      const s16x8 bf_ = *(const s16x8*)&Bb[cur][(n * 16 + lr) * 32 + lg * 8];
      acc[0][n] = __builtin_amdgcn_mfma_f32_16x16x32_bf16(af[0], bf_, acc[0][n], 0, 0, 0);
      acc[1][n] = __builtin_amdgcn_mfma_f32_16x16x32_bf16(af[1], bf_, acc[1][n], 0, 0, 0);
    }
    if (kt + 1 < NT) writeB(cur ^ 1);
    __syncthreads();
  }

  float bias_v[8];
  #pragma unroll
  for (int n = 0; n < 8; ++n) bias_v[n] = bias[n * 16 + lr];
  float invf[4];
  if (isq || isk) {
    #pragma unroll
    for (int n = 0; n < 4; ++n)
      invf[n] = __expf(-(float)(n * 16 + lr) * 0.21586735246819178f);
  }
  const int kvh = isq ? 0 : ((isk ? (n0 - NQ) : (n0 - NQ - 512)) >> 7);

  #pragma unroll
  for (int f = 0; f < 2; ++f)
    #pragma unroll
    for (int reg = 0; reg < 4; ++reg) {
      int m = m0 + w * 32 + f * 16 + lg * 4 + reg;
      float y[8];
      #pragma unroll
      for (int n = 0; n < 8; ++n) y[n] = acc[f][n][reg] + bias_v[n];
      if (isq || isk) {
        float p = (float)pos[m];
        #pragma unroll
        for (int n = 0; n < 4; ++n) {
          float sA, cA;
          __sincosf(p * invf[n], &sA, &cA);
          float lo = y[n], hi = y[n + 4];
          y[n]     = lo * cA - hi * sA;
          y[n + 4] = hi * cA + lo * sA;
        }
      }
      if (isq) {
        u16* dst = qbf + (size_t)m * NQ + n0;
        #pragma unroll
        for (int n = 0; n < 8; ++n) dst[n * 16 + lr] = f2bf(y[n] * QSCALE);
      } else {
        int b_ = m >> 10, s_ = m & 1023;
        size_t rowoff = ((size_t)(b_ * NKV + kvh) * TT + CC + s_) * HDIM;
        if (isk) {
          #pragma unroll
          for (int n = 0; n < 8; ++n) {
            nk[rowoff + n * 16 + lr]  = y[n];
            kbf[rowoff + n * 16 + lr] = f2bf(y[n]);
          }
        } else {
          size_t vb0 = (size_t)(b_ * NKV + kvh) * 128;
          #pragma unroll
          for (int n = 0; n < 8; ++n) {
            nv[rowoff + n * 16 + lr] = y[n];
            vbft[(vb0 + n * 16 + lr) * (size_t)TT + CC + s_] = f2bf(y[n]);
          }
        }
      }
    }
}

__global__ __launch_bounds__(256) void gemm_out_kernel(
    const u16* __restrict__ Abf, const float* __restrict__ W,
    float* __restrict__ Y) {
  __shared__ u16 Ab[2][128 * 32];
  __shared__ u16 Bb[2][128 * 32];
  const int tid = threadIdx.x;
  const int w = tid >> 6, lane = tid & 63, lr = lane & 15, lg = lane >> 4;
  const int m0 = blockIdx.y * 128, n0 = blockIdx.x * 128;

  f32x4 acc[2][8];
  #pragma unroll
  for (int f = 0; f < 2; ++f)
    #pragma unroll
    for (int n = 0; n < 8; ++n) acc[f][n] = (f32x4){0.f, 0.f, 0.f, 0.f};

  const int br = tid >> 1, bkh = (tid & 1) * 16;
  const float* Bsrc = W + (size_t)(n0 + br) * HIDDEN + bkh;

  auto stageA = [&](int buf, int k0) {
    #pragma unroll
    for (int i = 0; i < 2; ++i) {
      int ci = w * 128 + i * 64 + lane;
      int row = ci >> 2, c = ci & 3;
      __builtin_amdgcn_global_load_lds(
          (const __attribute__((address_space(1))) void*)(Abf + (size_t)(m0 + row) * HIDDEN + k0 + c * 8),
          (__attribute__((address_space(3))) void*)(&Ab[buf][(w * 128 + i * 64) * 8]),
          16, 0, 0);
    }
  };

  float4 fB[4];
  auto loadB = [&](int k0) {
    #pragma unroll
    for (int j = 0; j < 4; ++j) fB[j] = *(const float4*)(Bsrc + k0 + j * 4);
  };
  auto writeB = [&](int buf) {
    unsigned int pk[8];
    pk[0] = cvtpk(fB[0].x, fB[0].y); pk[1] = cvtpk(fB[0].z, fB[0].w);
    pk[2] = cvtpk(fB[1].x, fB[1].y); pk[3] = cvtpk(fB[1].z, fB[1].w);
    pk[4] = cvtpk(fB[2].x, fB[2].y); pk[5] = cvtpk(fB[2].z, fB[2].w);
    pk[6] = cvtpk(fB[3].x, fB[3].y); pk[7] = cvtpk(fB[3].z, fB[3].w);
    *(uint4*)&Bb[buf][br * 32 + bkh]     = make_uint4(pk[0], pk[1], pk[2], pk[3]);
    *(uint4*)&Bb[buf][br * 32 + bkh + 8] = make_uint4(pk[4], pk[5], pk[6], pk[7]);
  };

  stageA(0, 0); loadB(0); writeB(0);
  __syncthreads();

  for (int kt = 0; kt < NT; ++kt) {
    const int cur = kt & 1;
    if (kt + 1 < NT) { stageA(cur ^ 1, (kt + 1) * 32); loadB((kt + 1) * 32); }
    s16x8 af[2];
    af[0] = *(const s16x8*)&Ab[cur][(w * 32 + lr) * 32 + lg * 8];
    af[1] = *(const s16x8*)&Ab[cur][(w * 32 + 16 + lr) * 32 + lg * 8];
    #pragma unroll
    for (int n = 0; n < 8; ++n) {
      const s16x8 bf_ = *(const s16x8*)&Bb[cur][(n * 16 + lr) * 32 + lg * 8];
      acc[0][n] = __builtin_amdgcn_mfma_f32_16x16x32_bf16(af[0], bf_, acc[0][n], 0, 0, 0);
      acc[1][n] = __builtin_amdgcn_mfma_f32_16x16x32_bf16(af[1], bf_, acc[1][n], 0, 0, 0);
    }
    if (kt + 1 < NT) writeB(cur ^ 1);
    __syncthreads();
  }

  #pragma unroll
  for (int f = 0; f < 2; ++f)
    #pragma unroll
    for (int reg = 0; reg < 4; ++reg) {
      int m = m0 + w * 32 + f * 16 + lg * 4 + reg;
      float* dst = Y + (size_t)m * NQ + n0;
      #pragma unroll
      for (int n = 0; n < 8; ++n) dst[n * 16 + lr] = acc[f][n][reg];
    }
}

// ---- MFMA flash attention: 8 waves = 2 quads, KV-split, BKV=32, dbuf ------
// K rows kv-permuted in LDS so QK^T C-frag == PV A-frag (P stays in regs).
// V chunk-swizzled (f(row) = (row>>1)&3) -> PV ds_read_b128 is 2-way (free).
// exp via raw v_exp_f32 (log2e folded into q scale).
__global__ __launch_bounds__(512, 2) void attn_kernel(
    const u16* __restrict__ qbf, const u16* __restrict__ kbf,
    const u16* __restrict__ vbft, u16* __restrict__ aout) {
  __shared__ __align__(16) u16 SMEM[34816];  // 68 KB

  const int orig = blockIdx.x;              // 224 = 8 XCD-chunks of 28
  const int swzb = (orig & 7) * 28 + (orig >> 3);
  const int g    = swzb / 28;
  const int ii   = swzb % 28;
  const int b    = g >> 2;
  const int hkv  = g & 3;
  const int h    = hkv * GROUPS + (ii >> 2);
  const int q0   = (ii & 3) * 256;

  const int tid  = threadIdx.x;
  const int w    = tid >> 6;
  const int quad = w >> 2;
  const int wq   = w & 3;
  const int lane = tid & 63;
  const int lr   = lane & 15;
  const int lg   = lane >> 4;
  const int qw0  = q0 + wq * 64;

  s16x8 qf[4][4];
  #pragma unroll
  for (int fq = 0; fq < 4; ++fq) {
    const u16* qp = qbf + (size_t)(b * SS + qw0 + fq * 16 + lr) * NQ + h * HDIM + lg * 8;
    #pragma unroll
    for (int kk = 0; kk < 4; ++kk) qf[fq][kk] = *(const s16x8*)(qp + kk * 32);
  }

  const size_t bh = (size_t)(b * NKV + hkv);
  const u16* kB = kbf  + bh * (size_t)TT * HDIM;
  const u16* vB = vbft + bh * (size_t)HDIM * TT;

  f32x4 oacc[4][8];
  #pragma unroll
  for (int fq = 0; fq < 4; ++fq)
    #pragma unroll
    for (int n = 0; n < 8; ++n) oacc[fq][n] = (f32x4){0.f, 0.f, 0.f, 0.f};
  float lsum[4] = {0.f, 0.f, 0.f, 0.f};

  u16* Ksq = SMEM + quad * 8192;
  u16* Vsq = SMEM + 16384 + quad * 8192;

  auto stage = [&](int buf, int kt) {
    #pragma unroll
    for (int i = 0; i < 2; ++i) {
      int ci = (wq * 2 + i) * 64 + lane;
      // K: dest slot s = ci>>4; source row kv = sigma^-1(s)
      int s = ci >> 4, kc_ = ci & 15;
      int kv = (((s >> 3) & 1) << 4) | (((s >> 2) & 1) << 3)
             | (((s >> 4) & 1) << 2) | (s & 3);
      const u16* ksrc = kB + (size_t)(kt * 32 + kv) * HDIM + ((kc_ ^ (s & 7)) * 8);
      __builtin_amdgcn_global_load_lds(
          (const __attribute__((address_space(1))) void*)ksrc,
          (__attribute__((address_space(3))) void*)(Ksq + buf * 4096 + (wq * 2 + i) * 512),
          16, 0, 0);
      // V: dest (row vd, chunk vc_) holds source chunk vc_ ^ ((vd>>1)&3)
      int vd = ci >> 2, vc_ = ci & 3;
      const u16* vsrc = vB + (size_t)vd * TT + kt * 32 + ((vc_ ^ ((vd >> 1) & 3)) * 8);
      __builtin_amdgcn_global_load_lds(
          (const __attribute__((address_space(1))) void*)vsrc,
          (__attribute__((address_space(3))) void*)(Vsq + buf * 4096 + (wq * 2 + i) * 512),
          16, 0, 0);
    }
  };

  const int tbase = quad * 64;
  stage(0, tbase);
  __syncthreads();

  for (int it = 0; it < 64; ++it) {
    const int cur = it & 1;
    if (it + 1 < 64) stage(cur ^ 1, tbase + it + 1);

    // ---- QK^T (swapped): D col = q, rows = permuted kv slots ----
    f32x4 sacc[4][2];
    #pragma unroll
    for (int fq = 0; fq < 4; ++fq)
      #pragma unroll
      for (int n = 0; n < 2; ++n) sacc[fq][n] = (f32x4){0.f, 0.f, 0.f, 0.f};
    __builtin_amdgcn_s_setprio(1);
    #pragma unroll
    for (int kk = 0; kk < 4; ++kk) {
      #pragma unroll
      for (int n = 0; n < 2; ++n) {
        int row = n * 16 + lr;
        const s16x8 kf = *(const s16x8*)&Ksq[cur * 4096 + row * 128 + (((kk * 4 + lg) ^ (row & 7)) * 8)];
        #pragma unroll
        for (int fq = 0; fq < 4; ++fq)
          sacc[fq][n] = __builtin_amdgcn_mfma_f32_16x16x32_bf16(kf, qf[fq][kk], sacc[fq][n], 0, 0, 0);
      }
    }
    __builtin_amdgcn_s_setprio(0);

    // ---- fixed-offset softmax: single v_exp_f32 per element --------------
    s16x8 pa[4];
    #pragma unroll
    for (int fq = 0; fq < 4; ++fq) {
      float p00 = exp2_raw(sacc[fq][0][0] - SM_OFF2);
      float p01 = exp2_raw(sacc[fq][0][1] - SM_OFF2);
      float p02 = exp2_raw(sacc[fq][0][2] - SM_OFF2);
      float p03 = exp2_raw(sacc[fq][0][3] - SM_OFF2);
      float p10 = exp2_raw(sacc[fq][1][0] - SM_OFF2);
      float p11 = exp2_raw(sacc[fq][1][1] - SM_OFF2);
      float p12 = exp2_raw(sacc[fq][1][2] - SM_OFF2);
      float p13 = exp2_raw(sacc[fq][1][3] - SM_OFF2);
      lsum[fq] += ((p00 + p01) + (p02 + p03)) + ((p10 + p11) + (p12 + p13));
      uint4 pk4 = make_uint4(cvtpk(p00, p01), cvtpk(p02, p03),
                             cvtpk(p10, p11), cvtpk(p12, p13));
      pa[fq] = *(s16x8*)&pk4;
    }

    // ---- PV: O[q][d] += P[q][kv] * V^T[d][kv], k = 32 ----
    __builtin_amdgcn_s_setprio(1);
    #pragma unroll
    for (int n = 0; n < 8; ++n) {
      int row = n * 16 + lr;
      const s16x8 vf = *(const s16x8*)&Vsq[cur * 4096 + row * 32 + ((lg ^ ((row >> 1) & 3)) * 8)];
      #pragma unroll
      for (int fq = 0; fq < 4; ++fq)
        oacc[fq][n] = __builtin_amdgcn_mfma_f32_16x16x32_bf16(pa[fq], vf, oacc[fq][n], 0, 0, 0);
    }
    __builtin_amdgcn_s_setprio(0);

    __syncthreads();   // full drain: next-tile loads landed; all waves done with cur
  }

  // ---- combine quads (exact: partials additive), then finalize ----
  f32x4* OX = (f32x4*)SMEM;              // 64 KB (Ks+Vs dead)
  float* LX = (float*)(SMEM + 32768);    // 4 KB tail
  #pragma unroll
  for (int half = 0; half < 2; ++half) {
    if (quad == 1) {
      #pragma unroll
      for (int fp = 0; fp < 2; ++fp) {
        int fq = half * 2 + fp;
        #pragma unroll
        for (int n = 0; n < 8; ++n)
          OX[(fp * 8 + n) * 256 + wq * 64 + lane] = oacc[fq][n];
      }
      if (half == 0) {
        #pragma unroll
        for (int fq = 0; fq < 4; ++fq) LX[fq * 256 + wq * 64 + lane] = lsum[fq];
      }
    }
    __syncthreads();
    if (quad == 0) {
      #pragma unroll
      for (int fp = 0; fp < 2; ++fp) {
        int fq = half * 2 + fp;
        #pragma unroll
        for (int n = 0; n < 8; ++n) {
          f32x4 v = OX[(fp * 8 + n) * 256 + wq * 64 + lane];
          oacc[fq][n] += v;
        }
      }
      if (half == 0) {
        #pragma unroll
        for (int fq = 0; fq < 4; ++fq) lsum[fq] += LX[fq * 256 + wq * 64 + lane];
      }
    }
    __syncthreads();
  }

  if (quad == 0) {
    #pragma unroll
    for (int fq = 0; fq < 4; ++fq) {
      float s = lsum[fq];
      s += __shfl_xor(s, 16);
      s += __shfl_xor(s, 32);            // every lane: total for q = lr
      #pragma unroll
      for (int reg = 0; reg < 4; ++reg) {
        int qrow = lg * 4 + reg;
        float invl = 1.f / __shfl(s, qrow);   // total for q = qrow
        u16* orow = aout + (size_t)(b * SS + qw0 + fq * 16 + qrow) * NQ + h * HDIM;
        #pragma unroll
        for (int n = 0; n < 8; ++n)
          orow[n * 16 + lr] = f2bf(oacc[fq][n][reg] * invl);
      }
    }
  }
}

extern "C" void kernel_launch(void* const* d_in, const int* in_sizes, int n_in,
                              void* d_out, int out_size, void* d_ws, size_t ws_size,
                              hipStream_t stream) {
  const int*   positions = (const int*)d_in[0];
  const float* hidden    = (const float*)d_in[1];
  const float* kcache    = (const float*)d_in[2];
  const float* vcache    = (const float*)d_in[3];
  const float* qw = (const float*)d_in[5];
  const float* qb = (const float*)d_in[6];
  const float* kw = (const float*)d_in[7];
  const float* kb = (const float*)d_in[8];
  const float* vw = (const float*)d_in[9];
  const float* vb = (const float*)d_in[10];
  const float* ow = (const float*)d_in[11];

  float* out = (float*)d_out;                        // [2048][3584]
  float* nk  = out + (size_t)BS * NQ;                // [2,4,4096,128] f32
  float* nv  = nk + (size_t)BB * NKV * TT * HDIM;

  u16* qbf  = (u16*)d_ws;                            // [2048][3584]
  u16* kbf  = qbf + (size_t)BS * NQ;                 // [8][4096][128]
  u16* vbft = kbf + (size_t)BB * NKV * TT * HDIM;    // [8][128][4096]
  u16* hbf  = vbft + (size_t)BB * NKV * HDIM * TT;   // [2048][3584] (aliased: aws)
  u16* aws  = hbf;
  u16* wqkv = hbf + (size_t)BS * NQ;                 // [4608][3584] bf16 (fast path)
  u16* owbf = wqkv;                                  // [3584][3584] bf16, aliases wqkv

  const size_t fast_need = ((size_t)BS * NQ * 2 + (size_t)BB * NKV * TT * HDIM * 2
                            + (size_t)(NQ + 1024) * HIDDEN) * sizeof(u16);
  const bool fast = ws_size >= fast_need;

  copy_cache_kernel<<<dim3(CC / 64, BB * NKV), 256, 0, stream>>>(
      (const float4*)kcache, (const float4*)vcache,
      (float4*)nk, (float4*)nv, kbf, vbft);
  cvt_bf16_kernel<<<(BS * HIDDEN / 4 + 255) / 256, 256, 0, stream>>>(
      (const float4*)hidden, hbf, BS * HIDDEN / 4);

  if (fast) {
    cvt_bf16_kernel<<<(NQ * HIDDEN / 4 + 255) / 256, 256, 0, stream>>>(
        (const float4*)qw, wqkv, NQ * HIDDEN / 4);
    cvt_bf16_kernel<<<(512 * HIDDEN / 4 + 255) / 256, 256, 0, stream>>>(
        (const float4*)kw, wqkv + (size_t)NQ * HIDDEN, 512 * HIDDEN / 4);
    cvt_bf16_kernel<<<(512 * HIDDEN / 4 + 255) / 256, 256, 0, stream>>>(
        (const float4*)vw, wqkv + (size_t)(NQ + 512) * HIDDEN, 512 * HIDDEN / 4);
    gemm_qkv_bf_kernel<<<dim3(36, 16), 256, 0, stream>>>(
        hbf, wqkv, qb, kb, vb, positions, qbf, nk, nv, kbf, vbft);
    cvt_bf16_kernel<<<(NQ * HIDDEN / 4 + 255) / 256, 256, 0, stream>>>(
        (const float4*)ow, owbf, NQ * HIDDEN / 4);
    attn_kernel<<<224, 512, 0, stream>>>(qbf, kbf, vbft, aws);
    gemm_out_bf_kernel<<<dim3(28, 16), 256, 0, stream>>>(aws, owbf, out);
  } else {
    gemm_qkv_kernel<<<dim3(36, 16), 256, 0, stream>>>(
        hbf, qw, qb, kw, kb, vw, vb, positions, qbf, nk, nv, kbf, vbft);
    attn_kernel<<<224, 512, 0, stream>>>(qbf, kbf, vbft, aws);
    gemm_out_kernel<<<dim3(28, 16), 256, 0, stream>>>(aws, ow, out);
  }
}